// Round 4
// baseline (28.200 us; speedup 1.0000x reference)
//
#include <hip/hip_runtime.h>
#include <cstdint>
#include <cstddef>

typedef _Float16 half8 __attribute__((ext_vector_type(8)));
typedef float f32x4 __attribute__((ext_vector_type(4)));

static constexpr int kN   = 256;          // state dim (N == K)
static constexpr int kKS  = 8;            // k-steps of 32
static constexpr int kNTb = 8;            // n-tiles per block (BN = 128)
static constexpr int kBM  = 128;          // rows per block (8 waves x 16)
static constexpr int kBN  = 128;          // cols per block
static constexpr size_t kLDS = (size_t)kBN * kN * 2;  // 64 KiB packed f16 A-half

// out[m][n] = sum_k c[m][k] * A_t[n][k] + b[n] * f[m]
// N-split: block (mb, nh) computes rows [mb*128,+128) x cols [nh*128,+128).
// 64 KiB LDS -> 2 blocks/CU co-resident; load/compute/store phases overlap
// across blocks. Single barrier guards only the A-stage; c is consumed per-ks.
__global__ __launch_bounds__(512, 4) void hippo_fused(
    const float* __restrict__ c, const float* __restrict__ f,
    const float* __restrict__ A_stacked, const float* __restrict__ Bst,
    const int* __restrict__ tptr, float* __restrict__ out)
{
    extern __shared__ char lds_raw[];
    _Float16* __restrict__ As = (_Float16*)lds_raw;

    const int tid  = threadIdx.x;
    const int l    = tid & 63;
    const int wid  = tid >> 6;          // 0..7
    const int lo16 = l & 15;
    const int hi4  = l >> 4;
    const int t    = tptr[0];

    const int bid = blockIdx.x;
    const int mb  = bid & 255;          // row-block: pair members 256 apart -> same XCD
    const int nh  = bid >> 8;           // 0..1  col half
    const int m0  = mb * kBM + wid * 16;
    const int n0  = nh * kBN;

    // ---- A-stage loads FIRST (oldest in VMEM queue -> ds_write waits only these)
    // unit u: (nt=u, ks=wid): reads A_t[n0 + u*16 + lo16][wid*32 + hi4*8 .. +8]
    const float* __restrict__ asrc =
        A_stacked + (size_t)t * kN * kN + (size_t)(n0 + lo16) * kN + wid * 32 + (hi4 << 3);
    f32x4 a0[kNTb], a1[kNTb];
    #pragma unroll
    for (int u = 0; u < kNTb; ++u) {
        const float* p = asrc + (size_t)u * 16 * kN;
        a0[u] = *(const f32x4*)p;
        a1[u] = *(const f32x4*)(p + 4);
    }

    // ---- c loads (HBM/L3): lane reads c[m0+lo16][ks*32 + hi4*8 .. +8]
    const float* __restrict__ cptr = c + (size_t)(m0 + lo16) * kN + (hi4 << 3);
    f32x4 cv0[kKS], cv1[kKS];
    #pragma unroll
    for (int ks = 0; ks < kKS; ++ks) {
        cv0[ks] = *(const f32x4*)(cptr + ks * 32);
        cv1[ks] = *(const f32x4*)(cptr + ks * 32 + 4);
    }

    // ---- bias preloads (tiny, epilogue-only) ----
    const float* __restrict__ brow = Bst + (size_t)t * kN + n0;
    float bvs[kNTb];
    #pragma unroll
    for (int nt = 0; nt < kNTb; ++nt) bvs[nt] = brow[nt * 16 + lo16];
    float fv[4];
    #pragma unroll
    for (int r = 0; r < 4; ++r) fv[r] = f[m0 + (hi4 << 2) + r];

    // ---- cvt + ds_write A (waits A loads only; c stays in flight) ----
    // LDS frag-linear: unit (nt=u, ks=wid, lane l) at ((u*8+wid)*64+l)*16 B = (u*512+tid)*16
    #pragma unroll
    for (int u = 0; u < kNTb; ++u) {
        half8 h;
        h[0] = (_Float16)a0[u][0]; h[1] = (_Float16)a0[u][1];
        h[2] = (_Float16)a0[u][2]; h[3] = (_Float16)a0[u][3];
        h[4] = (_Float16)a1[u][0]; h[5] = (_Float16)a1[u][1];
        h[6] = (_Float16)a1[u][2]; h[7] = (_Float16)a1[u][3];
        ((half8*)As)[u * 512 + tid] = h;
    }
    __syncthreads();   // guards LDS only; c-loads still in flight

    // ---- ks-outer MFMA: compute starts when cv[0] lands ----
    f32x4 acc[kNTb];
    #pragma unroll
    for (int i = 0; i < kNTb; ++i) acc[i] = (f32x4){0.f, 0.f, 0.f, 0.f};

    const half8* __restrict__ Bs = (const half8*)As;
    #pragma unroll
    for (int ks = 0; ks < kKS; ++ks) {
        half8 af;
        af[0] = (_Float16)cv0[ks][0]; af[1] = (_Float16)cv0[ks][1];
        af[2] = (_Float16)cv0[ks][2]; af[3] = (_Float16)cv0[ks][3];
        af[4] = (_Float16)cv1[ks][0]; af[5] = (_Float16)cv1[ks][1];
        af[6] = (_Float16)cv1[ks][2]; af[7] = (_Float16)cv1[ks][3];
        #pragma unroll
        for (int nt = 0; nt < kNTb; ++nt) {
            half8 bf = Bs[(nt * kKS + ks) * 64 + l];
            acc[nt] = __builtin_amdgcn_mfma_f32_16x16x32_f16(af, bf, acc[nt], 0, 0, 0);
        }
    }

    // ---- epilogue ----
    float* __restrict__ obase = out + (size_t)(m0 + (hi4 << 2)) * kN + n0 + lo16;
    #pragma unroll
    for (int nt = 0; nt < kNTb; ++nt) {
        #pragma unroll
        for (int r = 0; r < 4; ++r)
            obase[(size_t)r * kN + nt * 16] = acc[nt][r] + bvs[nt] * fv[r];
    }
}

extern "C" void kernel_launch(void* const* d_in, const int* in_sizes, int n_in,
                              void* d_out, int out_size, void* d_ws, size_t ws_size,
                              hipStream_t stream) {
    const float* c   = (const float*)d_in[0];
    const float* f   = (const float*)d_in[1];
    const float* A   = (const float*)d_in[2];
    const float* B   = (const float*)d_in[3];
    const int*   t   = (const int*)d_in[4];
    float* out = (float*)d_out;

    const int batch = in_sizes[0] / kN;   // 32768

    hipFuncSetAttribute((const void*)hippo_fused,
                        hipFuncAttributeMaxDynamicSharedMemorySize,
                        (int)kLDS);

    // grid: mb in [0,256) major, nh in {0,1} minor-by-256 so pair members share an XCD
    hipLaunchKernelGGL(hippo_fused, dim3((batch / kBM) * 2), dim3(512), kLDS, stream,
                       c, f, A, B, t, out);
}

// Round 5
// 24.350 us; speedup vs baseline: 1.1581x; 1.1581x over previous
//
#include <hip/hip_runtime.h>
#include <cstdint>
#include <cstddef>

typedef _Float16 half8 __attribute__((ext_vector_type(8)));
typedef float f32x4 __attribute__((ext_vector_type(4)));

static constexpr int kN  = 256;          // state dim (N == K)
static constexpr int kBM = 128;          // rows per block (8 waves x 16)
static constexpr size_t kLDS = (size_t)kN * kN * 2;  // 128 KiB packed f16 A

// out[m][n] = sum_k c[m][k] * A_t[n][k] + b[n] * f[m]
// One block per CU (128 KiB LDS). Phase-overlapped schedule:
//   A loads (L2) -> bias -> c loads (HBM, stay in flight)
//   cvt+ds_write A (waits A only) -> barrier
//   phase 1: ks 0..3 outer, nt inner  (starts at first c landing, 16-chain ILP)
//   phase 2: nt pairs, ks 4..7 chained, store immediately (writes stream w/ MFMA)
__global__ __launch_bounds__(512, 2) void hippo_fused(
    const float* __restrict__ c, const float* __restrict__ f,
    const float* __restrict__ A_stacked, const float* __restrict__ Bst,
    const int* __restrict__ tptr, float* __restrict__ out)
{
    extern __shared__ char lds_raw[];
    _Float16* __restrict__ As = (_Float16*)lds_raw;

    const int tid  = threadIdx.x;
    const int l    = tid & 63;
    const int wid  = tid >> 6;          // 0..7
    const int lo16 = l & 15;
    const int hi4  = l >> 4;
    const int t    = tptr[0];
    const int m0   = blockIdx.x * kBM + wid * 16;

    // ---- 1) A loads FIRST (oldest in VMEM queue; L2/L3-shared across blocks)
    // unit u = (nt=u, ks=wid): reads A_t[u*16 + lo16][wid*32 + hi4*8 .. +8]
    const float* __restrict__ asrc =
        A_stacked + (size_t)t * kN * kN + (size_t)lo16 * kN + wid * 32 + (hi4 << 3);
    f32x4 a0[16], a1[16];
    #pragma unroll
    for (int u = 0; u < 16; ++u) {
        const float* p = asrc + (size_t)u * 16 * kN;
        a0[u] = *(const f32x4*)p;
        a1[u] = *(const f32x4*)(p + 4);
    }

    // ---- 2) bias loads (older than c; never force a drain) ----
    const float* __restrict__ brow = Bst + (size_t)t * kN;
    float bvs[16];
    #pragma unroll
    for (int nt = 0; nt < 16; ++nt) bvs[nt] = brow[nt * 16 + lo16];
    float fv[4];
    #pragma unroll
    for (int r = 0; r < 4; ++r) fv[r] = f[m0 + (hi4 << 2) + r];

    // ---- 3) c loads (HBM; consumed per-ks in phase 1) ----
    const float* __restrict__ cptr = c + (size_t)(m0 + lo16) * kN + (hi4 << 3);
    f32x4 cv0[8], cv1[8];
    #pragma unroll
    for (int ks = 0; ks < 8; ++ks) {
        cv0[ks] = *(const f32x4*)(cptr + ks * 32);
        cv1[ks] = *(const f32x4*)(cptr + ks * 32 + 4);
    }

    // ---- 4) cvt + ds_write A (waits only the A loads; c stays in flight) ----
    // frag (nt=u, ks=wid, lane l) at byte offset (u*512 + tid)*16 — linear, conflict-free
    #pragma unroll
    for (int u = 0; u < 16; ++u) {
        half8 h;
        h[0] = (_Float16)a0[u][0]; h[1] = (_Float16)a0[u][1];
        h[2] = (_Float16)a0[u][2]; h[3] = (_Float16)a0[u][3];
        h[4] = (_Float16)a1[u][0]; h[5] = (_Float16)a1[u][1];
        h[6] = (_Float16)a1[u][2]; h[7] = (_Float16)a1[u][3];
        ((half8*)As)[u * 512 + tid] = h;
    }
    __syncthreads();   // guards LDS only; c-loads still in flight

    const half8* __restrict__ Bs = (const half8*)As;
    f32x4 acc[16];
    #pragma unroll
    for (int i = 0; i < 16; ++i) acc[i] = (f32x4){0.f, 0.f, 0.f, 0.f};

    // ---- phase 1: ks 0..3 outer, nt inner (16 independent chains) ----
    #pragma unroll
    for (int ks = 0; ks < 4; ++ks) {
        half8 af;
        af[0] = (_Float16)cv0[ks][0]; af[1] = (_Float16)cv0[ks][1];
        af[2] = (_Float16)cv0[ks][2]; af[3] = (_Float16)cv0[ks][3];
        af[4] = (_Float16)cv1[ks][0]; af[5] = (_Float16)cv1[ks][1];
        af[6] = (_Float16)cv1[ks][2]; af[7] = (_Float16)cv1[ks][3];
        #pragma unroll
        for (int nt = 0; nt < 16; ++nt) {
            half8 bf = Bs[(nt * 8 + ks) * 64 + l];
            acc[nt] = __builtin_amdgcn_mfma_f32_16x16x32_f16(af, bf, acc[nt], 0, 0, 0);
        }
    }

    // ---- phase 2: remaining af, then nt-pairs with streamed stores ----
    half8 af2[4];
    #pragma unroll
    for (int ks = 0; ks < 4; ++ks) {
        af2[ks][0] = (_Float16)cv0[4 + ks][0]; af2[ks][1] = (_Float16)cv0[4 + ks][1];
        af2[ks][2] = (_Float16)cv0[4 + ks][2]; af2[ks][3] = (_Float16)cv0[4 + ks][3];
        af2[ks][4] = (_Float16)cv1[4 + ks][0]; af2[ks][5] = (_Float16)cv1[4 + ks][1];
        af2[ks][6] = (_Float16)cv1[4 + ks][2]; af2[ks][7] = (_Float16)cv1[4 + ks][3];
    }

    float* __restrict__ obase = out + (size_t)(m0 + (hi4 << 2)) * kN + lo16;
    #pragma unroll
    for (int nt = 0; nt < 16; nt += 2) {
        #pragma unroll
        for (int ks = 0; ks < 4; ++ks) {
            half8 bf0 = Bs[(nt * 8 + 4 + ks) * 64 + l];
            half8 bf1 = Bs[((nt + 1) * 8 + 4 + ks) * 64 + l];
            acc[nt]     = __builtin_amdgcn_mfma_f32_16x16x32_f16(af2[ks], bf0, acc[nt], 0, 0, 0);
            acc[nt + 1] = __builtin_amdgcn_mfma_f32_16x16x32_f16(af2[ks], bf1, acc[nt + 1], 0, 0, 0);
        }
        #pragma unroll
        for (int r = 0; r < 4; ++r) {
            obase[(size_t)r * kN + nt * 16]       = acc[nt][r]     + bvs[nt] * fv[r];
            obase[(size_t)r * kN + (nt + 1) * 16] = acc[nt + 1][r] + bvs[nt + 1] * fv[r];
        }
    }
}

extern "C" void kernel_launch(void* const* d_in, const int* in_sizes, int n_in,
                              void* d_out, int out_size, void* d_ws, size_t ws_size,
                              hipStream_t stream) {
    const float* c   = (const float*)d_in[0];
    const float* f   = (const float*)d_in[1];
    const float* A   = (const float*)d_in[2];
    const float* B   = (const float*)d_in[3];
    const int*   t   = (const int*)d_in[4];
    float* out = (float*)d_out;

    const int batch = in_sizes[0] / kN;   // 32768

    hipFuncSetAttribute((const void*)hippo_fused,
                        hipFuncAttributeMaxDynamicSharedMemorySize,
                        (int)kLDS);

    hipLaunchKernelGGL(hippo_fused, dim3(batch / kBM), dim3(512), kLDS, stream,
                       c, f, A, B, t, out);
}